// Round 12
// baseline (121.763 us; speedup 1.0000x reference)
//
#include <hip/hip_runtime.h>
#include <math.h>

// Problem constants
#define H_GRID 32
#define W_GRID 64
#define NTOK   2048
#define NHEADS 8
#define HD     24
#define DIMC   192
#define BATCH  4

static constexpr float SCALE = 0.20412414523193154f; // 1/sqrt(24)

typedef unsigned short ushort;
typedef unsigned int   uint;
typedef __attribute__((ext_vector_type(8))) _Float16 f16x8;
typedef __attribute__((ext_vector_type(4))) float    f32x4;

static __device__ __forceinline__ float4 ld4(const float* p) { return *(const float4*)p; }

static __device__ __forceinline__ ushort f2h(float f) {
    _Float16 h = (_Float16)f;
    union { _Float16 h; ushort u; } c; c.h = h; return c.u;
}
static __device__ __forceinline__ float h2f(ushort u) {
    union { ushort u; _Float16 h; } c; c.u = u; return (float)c.h;
}

// ---------------------------------------------------------------------------
// cast_h: convert x, qkv_w, proj_w to fp16; zero-fill Q/K d-pads (24..31).
// ---------------------------------------------------------------------------
__global__ __launch_bounds__(256) void cast_h(const float* __restrict__ x,
                                              const float* __restrict__ wq,
                                              const float* __restrict__ wp,
                                              ushort* __restrict__ xh,
                                              ushort* __restrict__ wqh,
                                              ushort* __restrict__ wph,
                                              ushort* __restrict__ Qh,
                                              ushort* __restrict__ Kh) {
    const int i = blockIdx.x * 256 + threadIdx.x;
    if (i >= 430080) {
        const int ti = i - 430080;            // 0..131071
        ushort* dst = (ti >> 16) ? Kh : Qh;
        const int row = ti & 65535;
        const uint4 z = {0u, 0u, 0u, 0u};
        *(uint4*)&dst[(size_t)row * 32 + 24] = z;
        return;
    }
    const float* src; ushort* dh; int off;
    if (i < 393216)      { src = x;  dh = xh;  off = i; }
    else if (i < 420864) { src = wq; dh = wqh; off = i - 393216; }
    else                 { src = wp; dh = wph; off = i - 420864; }
    float4 v = ld4(src + (size_t)off * 4);
    *(ushort4*)(dh + (size_t)off * 4) =
        make_ushort4(f2h(v.x), f2h(v.y), f2h(v.z), f2h(v.w));
}

// ---------------------------------------------------------------------------
// QKV GEMM (fp16 MFMA): C = x @ W^T + bias -> attention-ready layouts:
//   Q/K: [bh][tok][32] fp16 (d-pads pre-zeroed), q scaled
//   V:   VT [bh][d(32 rows, 24 used)][2080] fp16, token offset +8
// A-frags hoisted (6 in flight) for latency overlap.   (unchanged from R11)
// ---------------------------------------------------------------------------
__global__ __launch_bounds__(256, 4) void gemm_qkv(const ushort* __restrict__ Ah,
                                                   const ushort* __restrict__ Wh,
                                                   const float* __restrict__ bias,
                                                   ushort* __restrict__ Qh,
                                                   ushort* __restrict__ Kh,
                                                   ushort* __restrict__ VTh) {
    __shared__ ushort Ws[64 * 200];   // W stage; reused as 64x68 transpose buf

    const int t    = threadIdx.x;
    const int wave = t >> 6, lane = t & 63;
    const int m0   = blockIdx.x * 64 + wave * 16;
    const int j0   = blockIdx.y * 64;
    const int n16  = lane & 15;
    const int kq   = lane >> 4;

    for (int i = t; i < 1536; i += 256) {
        const int r = i / 24, c = i - (i / 24) * 24;
        *(uint4*)&Ws[r * 200 + c * 8] = *(const uint4*)&Wh[(size_t)(j0 + r) * 192 + c * 8];
    }

    const ushort* ap = Ah + (size_t)(m0 + n16) * 192 + kq * 8;

    f16x8 af[6];
#pragma unroll
    for (int ks = 0; ks < 6; ks++) af[ks] = *(const f16x8*)(ap + ks * 32);

    f32x4 acc[4] = {f32x4{0,0,0,0}, f32x4{0,0,0,0}, f32x4{0,0,0,0}, f32x4{0,0,0,0}};

    __syncthreads();

#pragma unroll
    for (int ks = 0; ks < 6; ks++) {
#pragma unroll
        for (int nt = 0; nt < 4; nt++) {
            const f16x8 bf = *(const f16x8*)&Ws[(nt * 16 + n16) * 200 + kq * 8 + ks * 32];
            acc[nt] = __builtin_amdgcn_mfma_f32_16x16x32_f16(af[ks], bf, acc[nt], 0, 0, 0);
        }
    }

    const int band  = blockIdx.y / 3;         // 0=Q, 1=K, 2=V
    const int mrow0 = m0 + kq * 4;
    const int b_    = mrow0 >> 11;
    const int tok0  = mrow0 & 2047;

    if (band == 2) {                          // V -> VT[bh][d][2080]+8, direct
#pragma unroll
        for (int nt = 0; nt < 4; nt++) {
            const int col = j0 + nt * 16 + n16;
            const int lc  = col - 384;
            const int h_  = lc / 24;
            const int d_  = lc - h_ * 24;
            const float bv = bias[col];
            ushort vv[4];
#pragma unroll
            for (int r = 0; r < 4; r++) vv[r] = f2h(acc[nt][r] + bv);
            const size_t addr = ((size_t)(b_ * 8 + h_) * 32 + d_) * 2080 + 8 + tok0;
            *(ushort4*)&VTh[addr] = make_ushort4(vv[0], vv[1], vv[2], vv[3]);
        }
    } else {                                  // Q/K -> LDS transpose -> coalesced
        const float sc_ = band ? 1.0f : SCALE;
        __syncthreads();                      // W reads done; reuse Ws
#pragma unroll
        for (int nt = 0; nt < 4; nt++) {
            const int col = j0 + nt * 16 + n16;
            const float bv = bias[col];
#pragma unroll
            for (int r = 0; r < 4; r++) {
                Ws[(wave * 16 + kq * 4 + r) * 68 + nt * 16 + n16] =
                    f2h((acc[nt][r] + bv) * sc_);
            }
        }
        __syncthreads();
        ushort* dst = band ? Kh : Qh;
        const int lc0 = j0 - band * 192;      // 0, 64, or 128
#pragma unroll
        for (int it = 0; it < 4; it++) {
            const int item = t + 256 * it;    // 0..1023
            const int tokl = item >> 4;
            const int cg   = item & 15;
            const ushort4 v = *(const ushort4*)&Ws[tokl * 68 + cg * 4];
            const int lc = lc0 + cg * 4;
            const int h_ = lc / 24;
            const int d0 = lc - h_ * 24;
            const int m  = blockIdx.x * 64 + tokl;
            const size_t addr = ((size_t)((m >> 11) * 8 + h_) * 2048 + (m & 2047)) * 32 + d0;
            *(ushort4*)&dst[addr] = v;
        }
    }
}

// ---------------------------------------------------------------------------
// MFMA local attention (fp16), LDS-staged K/V^T (coalesced, deduplicated).
// One block (4 waves) per (b, head, 4x8 q-tile).
// Window: kh = qh0-3..qh0+6 (10 rows) x kw = [qw0-8, qw0+24) (32 cols)
//   -> 320 slots, slot = rr*32 + cc. OOB staged clamped (finite) + masked.
// Stage: K -> KP[320][36] (conflict-free), VT -> VTs[32][328]; both as uint4.
// QK^T from LDS; softmax (shuffle + partner-wave exchange); P overlays the
// dead K region after barrier1. PV from LDS. ~46 KB LDS -> 3 blocks/CU.
// ---------------------------------------------------------------------------
__global__ __launch_bounds__(256, 3) void attn_mfma(const ushort* __restrict__ Qh,
                                                    const ushort* __restrict__ Kh,
                                                    const ushort* __restrict__ VTh,
                                                    ushort* __restrict__ aws) {
    const int qtile = blockIdx.x;
    const int head  = blockIdx.y;
    const int b     = blockIdx.z;
    const int qh0   = (qtile >> 3) * 4;
    const int qw0   = (qtile & 7) * 8;
    const int kw0a  = qw0 - 8;

    const int t = threadIdx.x;
    const int w = t >> 6, lane = t & 63;
    const int n16 = lane & 15, quad = lane >> 4;
    const int bh = b * 8 + head;

    __shared__ ushort KP[320 * 36];   // K stage (23 KB); P[32][328] overlays after QK
    __shared__ ushort VTs[32 * 328];  // V^T stage (21 KB)
    __shared__ ushort Os[32 * 28];
    __shared__ float  mxbuf[64], sumbuf[64];

    const ushort* Qb  = Qh  + (size_t)bh * 65536;
    const ushort* Kb  = Kh  + (size_t)bh * 65536;
    const ushort* VTb = VTh + (size_t)bh * 66560;   // 32*2080

    // ---- stage K: 320 slots x 4 x 16B, dedup + coalesced-ish ----
    for (int i = t; i < 1280; i += 256) {
        const int slot = i >> 2, part = i & 3;
        const int rr = slot >> 5, cc = slot & 31;
        const int khv = qh0 - 3 + rr;
        const int kwv = kw0a + cc;
        const int tok = (min(max(khv, 0), 31) << 6) + min(max(kwv, 0), 63);
        *(uint4*)&KP[slot * 36 + part * 8] = *(const uint4*)&Kb[(size_t)tok * 32 + part * 8];
    }
    // ---- stage VT: 32 d-rows x 10 window-rows x 4 x 16B (aligned: +8 guard) ----
    for (int i = t; i < 1280; i += 256) {
        const int d = i / 40, rem = i - d * 40;
        const int rr = rem >> 2, chunk = rem & 3;
        const int kh_cl = min(max(qh0 - 3 + rr, 0), 31);
        const ushort* src = VTb + (size_t)d * 2080 + 8 + (kh_cl << 6) + kw0a + chunk * 8;
        *(uint4*)&VTs[d * 328 + rr * 32 + chunk * 8] = *(const uint4*)src;
    }

    const int mt = w >> 1, nth = w & 1;
    const int mrow = 16 * mt + n16;
    const int tq_a = ((qh0 + (mrow >> 3)) << 6) + qw0 + (mrow & 7);
    const f16x8 qf = *(const f16x8*)&Qb[(size_t)tq_a * 32 + quad * 8];

    __syncthreads();   // staging complete

    // ---- QK^T from LDS: 10 n-tiles per wave ----
    float sv[10][4];
    float mx4[4] = {-3e38f, -3e38f, -3e38f, -3e38f};
#pragma unroll
    for (int j = 0; j < 10; j++) {
        const int slot = (nth * 10 + j) * 16 + n16;
        const int rr = slot >> 5, cc = slot & 31;
        const int khv = qh0 - 3 + rr;
        const int kwv = kw0a + cc;
        const f16x8 kf = *(const f16x8*)&KP[slot * 36 + quad * 8];
        f32x4 a = f32x4{0, 0, 0, 0};
        a = __builtin_amdgcn_mfma_f32_16x16x32_f16(qf, kf, a, 0, 0, 0);
        const bool kok = (khv >= 0) && (khv < 32) && (kwv >= 0) && (kwv < 64);
#pragma unroll
        for (int r = 0; r < 4; r++) {
            const int m   = 16 * mt + quad * 4 + r;
            const int qhv = qh0 + (m >> 3);
            const int qwv = qw0 + (m & 7);
            const bool valid = kok && (abs(khv - qhv) <= 3) && (abs(kwv - qwv) <= 5);
            const float s = valid ? a[r] : -3e38f;
            sv[j][r] = s;
            mx4[r] = fmaxf(mx4[r], s);
        }
    }
#pragma unroll
    for (int d = 1; d < 16; d <<= 1)
#pragma unroll
        for (int r = 0; r < 4; r++) mx4[r] = fmaxf(mx4[r], __shfl_xor(mx4[r], d));
    if (n16 == 0) {
#pragma unroll
        for (int r = 0; r < 4; r++) mxbuf[w * 16 + quad * 4 + r] = mx4[r];
    }
    __syncthreads();   // barrier1: max exchange; K region now dead -> P overlay
#pragma unroll
    for (int r = 0; r < 4; r++) mx4[r] = fmaxf(mx4[r], mxbuf[(w ^ 1) * 16 + quad * 4 + r]);

    // ---- exp -> P (fp16, overlaying KP), sums of rounded p ----
    float sum4[4] = {0.f, 0.f, 0.f, 0.f};
#pragma unroll
    for (int j = 0; j < 10; j++) {
        const int slot = (nth * 10 + j) * 16 + n16;
#pragma unroll
        for (int r = 0; r < 4; r++) {
            const float p = __expf(sv[j][r] - mx4[r]);
            const ushort ph = f2h(p);
            sum4[r] += h2f(ph);
            KP[(16 * mt + quad * 4 + r) * 328 + slot] = ph;
        }
    }
#pragma unroll
    for (int d = 1; d < 16; d <<= 1)
#pragma unroll
        for (int r = 0; r < 4; r++) sum4[r] += __shfl_xor(sum4[r], d);
    if (n16 == 0) {
#pragma unroll
        for (int r = 0; r < 4; r++) sumbuf[w * 16 + quad * 4 + r] = sum4[r];
    }
    __syncthreads();   // barrier2: P + sums ready

    // ---- PV from LDS: 10 ksteps ----
    const int mtP = w >> 1, ntP = w & 1;
    const int dcol = 16 * ntP + n16;
    f32x4 acc = f32x4{0, 0, 0, 0};
#pragma unroll
    for (int ks = 0; ks < 10; ks++) {
        const f16x8 pa = *(const f16x8*)&KP[(16 * mtP + n16) * 328 + ks * 32 + quad * 8];
        const f16x8 vf = *(const f16x8*)&VTs[dcol * 328 + ks * 32 + quad * 8];
        acc = __builtin_amdgcn_mfma_f32_16x16x32_f16(pa, vf, acc, 0, 0, 0);
    }
    if (dcol < 24) {
#pragma unroll
        for (int r = 0; r < 4; r++) {
            const int m = 16 * mtP + quad * 4 + r;
            const float tot = sumbuf[(2 * mtP) * 16 + (m & 15)] +
                              sumbuf[(2 * mtP + 1) * 16 + (m & 15)];
            Os[m * 28 + dcol] = f2h(acc[r] / tot);
        }
    }
    __syncthreads();

    // ---- coalesced output: 32 tokens x 24 dims ----
    if (t < 192) {
        const int tok = t / 6, g = t - (t / 6) * 6;
        const ushort4 v = *(const ushort4*)&Os[tok * 28 + g * 4];
        const int tq = ((qh0 + (tok >> 3)) << 6) + qw0 + (tok & 7);
        *(ushort4*)&aws[((size_t)(b * 2048 + tq)) * 192 + head * 24 + g * 4] = v;
    }
}

// ---------------------------------------------------------------------------
// Proj GEMM (fp16 MFMA): out[8192x192] = aws @ Wp^T + bias (fp32 out).
// A-frags hoisted. 128-thr blocks, 32 rows each -> 768 blocks. (R11 verbatim)
// ---------------------------------------------------------------------------
__global__ __launch_bounds__(128, 4) void gemm_proj(const ushort* __restrict__ Ah,
                                                    const ushort* __restrict__ Wh,
                                                    const float* __restrict__ bias,
                                                    float* __restrict__ C) {
    __shared__ ushort Ws[64 * 200];

    const int t    = threadIdx.x;
    const int wave = t >> 6, lane = t & 63;
    const int m0   = blockIdx.x * 32 + wave * 16;
    const int j0   = blockIdx.y * 64;
    const int n16  = lane & 15;
    const int kq   = lane >> 4;

    for (int i = t; i < 1536; i += 128) {
        const int r = i / 24, c = i - (i / 24) * 24;
        *(uint4*)&Ws[r * 200 + c * 8] = *(const uint4*)&Wh[(size_t)(j0 + r) * 192 + c * 8];
    }

    const ushort* ap = Ah + (size_t)(m0 + n16) * 192 + kq * 8;

    f16x8 af[6];
#pragma unroll
    for (int ks = 0; ks < 6; ks++) af[ks] = *(const f16x8*)(ap + ks * 32);

    f32x4 acc[4] = {f32x4{0,0,0,0}, f32x4{0,0,0,0}, f32x4{0,0,0,0}, f32x4{0,0,0,0}};

    __syncthreads();

#pragma unroll
    for (int ks = 0; ks < 6; ks++) {
#pragma unroll
        for (int nt = 0; nt < 4; nt++) {
            const f16x8 bf = *(const f16x8*)&Ws[(nt * 16 + n16) * 200 + kq * 8 + ks * 32];
            acc[nt] = __builtin_amdgcn_mfma_f32_16x16x32_f16(af[ks], bf, acc[nt], 0, 0, 0);
        }
    }

#pragma unroll
    for (int nt = 0; nt < 4; nt++) {
        const int col = j0 + nt * 16 + n16;
        const float bv = bias[col];
#pragma unroll
        for (int r = 0; r < 4; r++) {
            const int m = m0 + kq * 4 + r;
            C[(size_t)m * 192 + col] = acc[nt][r] + bv;
        }
    }
}

// ---------------------------------------------------------------------------
// Launch: cast_h -> gemm_qkv -> attn_mfma -> gemm_proj
// ---------------------------------------------------------------------------
extern "C" void kernel_launch(void* const* d_in, const int* in_sizes, int n_in,
                              void* d_out, int out_size, void* d_ws, size_t ws_size,
                              hipStream_t stream) {
    const float* x      = (const float*)d_in[0];
    const float* qkv_w  = (const float*)d_in[1];
    const float* qkv_b  = (const float*)d_in[2];
    const float* proj_w = (const float*)d_in[3];
    const float* proj_b = (const float*)d_in[4];
    // d_in[5] mask: fixed 7x11 window, recomputed analytically; unused.

    char* wsb = (char*)d_ws;
    ushort* xh   = (ushort*)(wsb + 0);          // [8192,192] fp16
    ushort* wqh  = (ushort*)(wsb + 3145728);    // [576,192]
    ushort* wph  = (ushort*)(wsb + 3366912);    // [192,192]
    ushort* Qh   = (ushort*)(wsb + 3440640);    // [32,2048,32]
    ushort* Kh   = (ushort*)(wsb + 7634944);    // [32,2048,32]
    ushort* VTh  = (ushort*)(wsb + 11829248);   // [32,32,2080]
    ushort* awsh = (ushort*)(wsb + 16171008);   // [8192,192]
    float*  out  = (float*)d_out;

    hipLaunchKernelGGL(cast_h, dim3(2192), dim3(256), 0, stream,
                       x, qkv_w, proj_w, xh, wqh, wph, Qh, Kh);
    hipLaunchKernelGGL(gemm_qkv, dim3(128, 9), dim3(256), 0, stream,
                       xh, wqh, qkv_b, Qh, Kh, VTh);
    hipLaunchKernelGGL(attn_mfma, dim3(64, 8, 4), dim3(256), 0, stream,
                       Qh, Kh, VTh, awsh);
    hipLaunchKernelGGL(gemm_proj, dim3(256, 3), dim3(128), 0, stream,
                       awsh, wph, proj_b, out);
}

// Round 13
// 111.939 us; speedup vs baseline: 1.0878x; 1.0878x over previous
//
#include <hip/hip_runtime.h>
#include <math.h>

// Problem constants
#define H_GRID 32
#define W_GRID 64
#define NTOK   2048
#define NHEADS 8
#define HD     24
#define DIMC   192
#define BATCH  4

static constexpr float SCALE = 0.20412414523193154f; // 1/sqrt(24)

typedef unsigned short ushort;
typedef unsigned int   uint;
typedef __attribute__((ext_vector_type(8))) _Float16 f16x8;
typedef __attribute__((ext_vector_type(4))) float    f32x4;

static __device__ __forceinline__ float4 ld4(const float* p) { return *(const float4*)p; }

static __device__ __forceinline__ ushort f2h(float f) {
    _Float16 h = (_Float16)f;
    union { _Float16 h; ushort u; } c; c.h = h; return c.u;
}
static __device__ __forceinline__ float h2f(ushort u) {
    union { ushort u; _Float16 h; } c; c.u = u; return (float)c.h;
}

// ---------------------------------------------------------------------------
// cast_h: convert x, qkv_w, proj_w to fp16; zero-fill Q/K d-pads (24..31).
// ---------------------------------------------------------------------------
__global__ __launch_bounds__(256) void cast_h(const float* __restrict__ x,
                                              const float* __restrict__ wq,
                                              const float* __restrict__ wp,
                                              ushort* __restrict__ xh,
                                              ushort* __restrict__ wqh,
                                              ushort* __restrict__ wph,
                                              ushort* __restrict__ Qh,
                                              ushort* __restrict__ Kh) {
    const int i = blockIdx.x * 256 + threadIdx.x;
    if (i >= 430080) {
        const int ti = i - 430080;            // 0..131071
        ushort* dst = (ti >> 16) ? Kh : Qh;
        const int row = ti & 65535;
        const uint4 z = {0u, 0u, 0u, 0u};
        *(uint4*)&dst[(size_t)row * 32 + 24] = z;
        return;
    }
    const float* src; ushort* dh; int off;
    if (i < 393216)      { src = x;  dh = xh;  off = i; }
    else if (i < 420864) { src = wq; dh = wqh; off = i - 393216; }
    else                 { src = wp; dh = wph; off = i - 420864; }
    float4 v = ld4(src + (size_t)off * 4);
    *(ushort4*)(dh + (size_t)off * 4) =
        make_ushort4(f2h(v.x), f2h(v.y), f2h(v.z), f2h(v.w));
}

// ---------------------------------------------------------------------------
// QKV GEMM (fp16 MFMA): C = x @ W^T + bias -> attention-ready layouts:
//   Q/K: [bh][tok][32] fp16 (d-pads pre-zeroed), q scaled
//   V:   VT [bh][d(32 rows, 24 used)][2080] fp16, token offset +8
// A-frags hoisted (6 in flight) for latency overlap.   (R11 verbatim)
// ---------------------------------------------------------------------------
__global__ __launch_bounds__(256, 4) void gemm_qkv(const ushort* __restrict__ Ah,
                                                   const ushort* __restrict__ Wh,
                                                   const float* __restrict__ bias,
                                                   ushort* __restrict__ Qh,
                                                   ushort* __restrict__ Kh,
                                                   ushort* __restrict__ VTh) {
    __shared__ ushort Ws[64 * 200];   // W stage; reused as 64x68 transpose buf

    const int t    = threadIdx.x;
    const int wave = t >> 6, lane = t & 63;
    const int m0   = blockIdx.x * 64 + wave * 16;
    const int j0   = blockIdx.y * 64;
    const int n16  = lane & 15;
    const int kq   = lane >> 4;

    for (int i = t; i < 1536; i += 256) {
        const int r = i / 24, c = i - (i / 24) * 24;
        *(uint4*)&Ws[r * 200 + c * 8] = *(const uint4*)&Wh[(size_t)(j0 + r) * 192 + c * 8];
    }

    const ushort* ap = Ah + (size_t)(m0 + n16) * 192 + kq * 8;

    f16x8 af[6];
#pragma unroll
    for (int ks = 0; ks < 6; ks++) af[ks] = *(const f16x8*)(ap + ks * 32);

    f32x4 acc[4] = {f32x4{0,0,0,0}, f32x4{0,0,0,0}, f32x4{0,0,0,0}, f32x4{0,0,0,0}};

    __syncthreads();

#pragma unroll
    for (int ks = 0; ks < 6; ks++) {
#pragma unroll
        for (int nt = 0; nt < 4; nt++) {
            const f16x8 bf = *(const f16x8*)&Ws[(nt * 16 + n16) * 200 + kq * 8 + ks * 32];
            acc[nt] = __builtin_amdgcn_mfma_f32_16x16x32_f16(af[ks], bf, acc[nt], 0, 0, 0);
        }
    }

    const int band  = blockIdx.y / 3;         // 0=Q, 1=K, 2=V
    const int mrow0 = m0 + kq * 4;
    const int b_    = mrow0 >> 11;
    const int tok0  = mrow0 & 2047;

    if (band == 2) {                          // V -> VT[bh][d][2080]+8, direct
#pragma unroll
        for (int nt = 0; nt < 4; nt++) {
            const int col = j0 + nt * 16 + n16;
            const int lc  = col - 384;
            const int h_  = lc / 24;
            const int d_  = lc - h_ * 24;
            const float bv = bias[col];
            ushort vv[4];
#pragma unroll
            for (int r = 0; r < 4; r++) vv[r] = f2h(acc[nt][r] + bv);
            const size_t addr = ((size_t)(b_ * 8 + h_) * 32 + d_) * 2080 + 8 + tok0;
            *(ushort4*)&VTh[addr] = make_ushort4(vv[0], vv[1], vv[2], vv[3]);
        }
    } else {                                  // Q/K -> LDS transpose -> coalesced
        const float sc_ = band ? 1.0f : SCALE;
        __syncthreads();                      // W reads done; reuse Ws
#pragma unroll
        for (int nt = 0; nt < 4; nt++) {
            const int col = j0 + nt * 16 + n16;
            const float bv = bias[col];
#pragma unroll
            for (int r = 0; r < 4; r++) {
                Ws[(wave * 16 + kq * 4 + r) * 68 + nt * 16 + n16] =
                    f2h((acc[nt][r] + bv) * sc_);
            }
        }
        __syncthreads();
        ushort* dst = band ? Kh : Qh;
        const int lc0 = j0 - band * 192;      // 0, 64, or 128
#pragma unroll
        for (int it = 0; it < 4; it++) {
            const int item = t + 256 * it;    // 0..1023
            const int tokl = item >> 4;
            const int cg   = item & 15;
            const ushort4 v = *(const ushort4*)&Ws[tokl * 68 + cg * 4];
            const int lc = lc0 + cg * 4;
            const int h_ = lc / 24;
            const int d0 = lc - h_ * 24;
            const int m  = blockIdx.x * 64 + tokl;
            const size_t addr = ((size_t)((m >> 11) * 8 + h_) * 2048 + (m & 2047)) * 32 + d0;
            *(ushort4*)&dst[addr] = v;
        }
    }
}

// ---------------------------------------------------------------------------
// MFMA local attention (fp16), direct global gathers (R11 structure) with an
// XCD-aware 1D swizzle: blockIdx.x & 7 = head, so the %8 round-robin
// block->XCD assignment pins each head's 256 blocks to one XCD; per-head
// K+Q+VT slice (~1.6 MB over 4 batches) then fits that XCD's 4 MB L2.
// K-frag and VT-frag gathers hoisted in batches of 5 (latency overlap).
// ---------------------------------------------------------------------------
__global__ __launch_bounds__(256, 4) void attn_mfma(const ushort* __restrict__ Qh,
                                                    const ushort* __restrict__ Kh,
                                                    const ushort* __restrict__ VTh,
                                                    ushort* __restrict__ aws) {
    const int id    = blockIdx.x;          // 0..2047
    const int head  = id & 7;              // -> XCD (id % 8 round-robin)
    const int qtile = (id >> 3) & 63;
    const int b     = id >> 9;
    const int qh0   = (qtile >> 3) * 4;
    const int qw0   = (qtile & 7) * 8;
    const int kw0a  = qw0 - 8;

    const int t = threadIdx.x;
    const int w = t >> 6, lane = t & 63;
    const int n16 = lane & 15, quad = lane >> 4;
    const int bh = b * 8 + head;

    __shared__ ushort P[32 * 328];
    __shared__ ushort Os[32 * 28];
    __shared__ float  mxbuf[64], sumbuf[64];

    const ushort* Qb = Qh + (size_t)bh * 65536;
    const ushort* Kb = Kh + (size_t)bh * 65536;

    const int mt = w >> 1, nth = w & 1;
    const int mrow = 16 * mt + n16;
    const int tq_a = ((qh0 + (mrow >> 3)) << 6) + qw0 + (mrow & 7);
    const f16x8 qf = *(const f16x8*)&Qb[(size_t)tq_a * 32 + quad * 8];

    float sv[10][4];
    float mx4[4] = {-3e38f, -3e38f, -3e38f, -3e38f};
#pragma unroll
    for (int half = 0; half < 2; half++) {
        f16x8 kf[5];
        int khvv[5], kwvv[5];
#pragma unroll
        for (int jj = 0; jj < 5; jj++) {       // 5 gathers in flight
            const int j = half * 5 + jj;
            const int slot = (nth * 10 + j) * 16 + n16;
            const int rr = slot >> 5, cc = slot & 31;
            khvv[jj] = qh0 - 3 + rr;
            kwvv[jj] = kw0a + cc;
            const int tok = (min(max(khvv[jj], 0), 31) << 6) + min(max(kwvv[jj], 0), 63);
            kf[jj] = *(const f16x8*)&Kb[(size_t)tok * 32 + quad * 8];
        }
#pragma unroll
        for (int jj = 0; jj < 5; jj++) {
            const int j = half * 5 + jj;
            f32x4 a = f32x4{0, 0, 0, 0};
            a = __builtin_amdgcn_mfma_f32_16x16x32_f16(qf, kf[jj], a, 0, 0, 0);
            const int khv = khvv[jj], kwv = kwvv[jj];
            const bool kok = (khv >= 0) && (khv < 32) && (kwv >= 0) && (kwv < 64);
#pragma unroll
            for (int r = 0; r < 4; r++) {
                const int m   = 16 * mt + quad * 4 + r;
                const int qhv = qh0 + (m >> 3);
                const int qwv = qw0 + (m & 7);
                const bool valid = kok && (abs(khv - qhv) <= 3) && (abs(kwv - qwv) <= 5);
                const float s = valid ? a[r] : -3e38f;
                sv[j][r] = s;
                mx4[r] = fmaxf(mx4[r], s);
            }
        }
    }
#pragma unroll
    for (int d = 1; d < 16; d <<= 1)
#pragma unroll
        for (int r = 0; r < 4; r++) mx4[r] = fmaxf(mx4[r], __shfl_xor(mx4[r], d));
    if (n16 == 0) {
#pragma unroll
        for (int r = 0; r < 4; r++) mxbuf[w * 16 + quad * 4 + r] = mx4[r];
    }
    __syncthreads();
#pragma unroll
    for (int r = 0; r < 4; r++) mx4[r] = fmaxf(mx4[r], mxbuf[(w ^ 1) * 16 + quad * 4 + r]);

    float sum4[4] = {0.f, 0.f, 0.f, 0.f};
#pragma unroll
    for (int j = 0; j < 10; j++) {
        const int slot = (nth * 10 + j) * 16 + n16;
#pragma unroll
        for (int r = 0; r < 4; r++) {
            const float p = __expf(sv[j][r] - mx4[r]);
            const ushort ph = f2h(p);
            sum4[r] += h2f(ph);
            P[(16 * mt + quad * 4 + r) * 328 + slot] = ph;
        }
    }
#pragma unroll
    for (int d = 1; d < 16; d <<= 1)
#pragma unroll
        for (int r = 0; r < 4; r++) sum4[r] += __shfl_xor(sum4[r], d);
    if (n16 == 0) {
#pragma unroll
        for (int r = 0; r < 4; r++) sumbuf[w * 16 + quad * 4 + r] = sum4[r];
    }
    __syncthreads();

    // ---- PV: VT gathers hoisted in batches of 5 ----
    const int mtP = w >> 1, ntP = w & 1;
    const int dcol = 16 * ntP + n16;
    const ushort* VTb = VTh + (size_t)bh * 66560;    // 32*2080
    f32x4 acc = f32x4{0, 0, 0, 0};
#pragma unroll
    for (int half = 0; half < 2; half++) {
        f16x8 vf[5], pa[5];
#pragma unroll
        for (int kk = 0; kk < 5; kk++) {
            const int ks = half * 5 + kk;
            const int kh_cl = min(max(qh0 - 3 + ks, 0), 31);
            vf[kk] = *(const f16x8*)&VTb[(size_t)dcol * 2080 + 8 + (kh_cl << 6) + kw0a + quad * 8];
            pa[kk] = *(const f16x8*)&P[(16 * mtP + n16) * 328 + ks * 32 + quad * 8];
        }
#pragma unroll
        for (int kk = 0; kk < 5; kk++) {
            acc = __builtin_amdgcn_mfma_f32_16x16x32_f16(pa[kk], vf[kk], acc, 0, 0, 0);
        }
    }
    if (dcol < 24) {
#pragma unroll
        for (int r = 0; r < 4; r++) {
            const int m = 16 * mtP + quad * 4 + r;
            const float tot = sumbuf[(2 * mtP) * 16 + (m & 15)] +
                              sumbuf[(2 * mtP + 1) * 16 + (m & 15)];
            Os[m * 28 + dcol] = f2h(acc[r] / tot);
        }
    }
    __syncthreads();

    // ---- coalesced output: 32 tokens x 24 dims ----
    if (t < 192) {
        const int tok = t / 6, g = t - (t / 6) * 6;
        const ushort4 v = *(const ushort4*)&Os[tok * 28 + g * 4];
        const int tq = ((qh0 + (tok >> 3)) << 6) + qw0 + (tok & 7);
        *(ushort4*)&aws[((size_t)(b * 2048 + tq)) * 192 + head * 24 + g * 4] = v;
    }
}

// ---------------------------------------------------------------------------
// Proj GEMM (fp16 MFMA): out[8192x192] = aws @ Wp^T + bias (fp32 out).
// A-frags hoisted. 128-thr blocks, 32 rows each -> 768 blocks. (R11 verbatim)
// ---------------------------------------------------------------------------
__global__ __launch_bounds__(128, 4) void gemm_proj(const ushort* __restrict__ Ah,
                                                    const ushort* __restrict__ Wh,
                                                    const float* __restrict__ bias,
                                                    float* __restrict__ C) {
    __shared__ ushort Ws[64 * 200];

    const int t    = threadIdx.x;
    const int wave = t >> 6, lane = t & 63;
    const int m0   = blockIdx.x * 32 + wave * 16;
    const int j0   = blockIdx.y * 64;
    const int n16  = lane & 15;
    const int kq   = lane >> 4;

    for (int i = t; i < 1536; i += 128) {
        const int r = i / 24, c = i - (i / 24) * 24;
        *(uint4*)&Ws[r * 200 + c * 8] = *(const uint4*)&Wh[(size_t)(j0 + r) * 192 + c * 8];
    }

    const ushort* ap = Ah + (size_t)(m0 + n16) * 192 + kq * 8;

    f16x8 af[6];
#pragma unroll
    for (int ks = 0; ks < 6; ks++) af[ks] = *(const f16x8*)(ap + ks * 32);

    f32x4 acc[4] = {f32x4{0,0,0,0}, f32x4{0,0,0,0}, f32x4{0,0,0,0}, f32x4{0,0,0,0}};

    __syncthreads();

#pragma unroll
    for (int ks = 0; ks < 6; ks++) {
#pragma unroll
        for (int nt = 0; nt < 4; nt++) {
            const f16x8 bf = *(const f16x8*)&Ws[(nt * 16 + n16) * 200 + kq * 8 + ks * 32];
            acc[nt] = __builtin_amdgcn_mfma_f32_16x16x32_f16(af[ks], bf, acc[nt], 0, 0, 0);
        }
    }

#pragma unroll
    for (int nt = 0; nt < 4; nt++) {
        const int col = j0 + nt * 16 + n16;
        const float bv = bias[col];
#pragma unroll
        for (int r = 0; r < 4; r++) {
            const int m = m0 + kq * 4 + r;
            C[(size_t)m * 192 + col] = acc[nt][r] + bv;
        }
    }
}

// ---------------------------------------------------------------------------
// Launch: cast_h -> gemm_qkv -> attn_mfma (XCD-swizzled 1D grid) -> gemm_proj
// ---------------------------------------------------------------------------
extern "C" void kernel_launch(void* const* d_in, const int* in_sizes, int n_in,
                              void* d_out, int out_size, void* d_ws, size_t ws_size,
                              hipStream_t stream) {
    const float* x      = (const float*)d_in[0];
    const float* qkv_w  = (const float*)d_in[1];
    const float* qkv_b  = (const float*)d_in[2];
    const float* proj_w = (const float*)d_in[3];
    const float* proj_b = (const float*)d_in[4];
    // d_in[5] mask: fixed 7x11 window, recomputed analytically; unused.

    char* wsb = (char*)d_ws;
    ushort* xh   = (ushort*)(wsb + 0);          // [8192,192] fp16
    ushort* wqh  = (ushort*)(wsb + 3145728);    // [576,192]
    ushort* wph  = (ushort*)(wsb + 3366912);    // [192,192]
    ushort* Qh   = (ushort*)(wsb + 3440640);    // [32,2048,32]
    ushort* Kh   = (ushort*)(wsb + 7634944);    // [32,2048,32]
    ushort* VTh  = (ushort*)(wsb + 11829248);   // [32,32,2080]
    ushort* awsh = (ushort*)(wsb + 16171008);   // [8192,192]
    float*  out  = (float*)d_out;

    hipLaunchKernelGGL(cast_h, dim3(2192), dim3(256), 0, stream,
                       x, qkv_w, proj_w, xh, wqh, wph, Qh, Kh);
    hipLaunchKernelGGL(gemm_qkv, dim3(128, 9), dim3(256), 0, stream,
                       xh, wqh, qkv_b, Qh, Kh, VTh);
    hipLaunchKernelGGL(attn_mfma, dim3(2048), dim3(256), 0, stream,
                       Qh, Kh, VTh, awsh);
    hipLaunchKernelGGL(gemm_proj, dim3(256, 3), dim3(128), 0, stream,
                       awsh, wph, proj_b, out);
}